// Round 19
// baseline (2718.296 us; speedup 1.0000x reference)
//
#include <hip/hip_runtime.h>

constexpr int C_NTOK = 4096;   // B*S
constexpr int C_DIM  = 1024;
constexpr int C_NL   = 8;
constexpr int C_NH   = 16;
constexpr int C_NKVH = 8;
constexpr int C_FF   = 4096;
constexpr int C_HD   = 64;
constexpr int C_B    = 2;
constexpr int C_S    = 2048;
constexpr int C_V    = 4054;
constexpr int C_PAD  = 4053;

typedef unsigned short u16;
typedef unsigned int   u32;
typedef __attribute__((ext_vector_type(4))) float f32x4;
typedef __attribute__((ext_vector_type(8))) short s16x8;

__device__ __forceinline__ float bf2f(u16 u) {
  u32 i = ((u32)u) << 16; float f; __builtin_memcpy(&f, &i, 4); return f;
}
__device__ __forceinline__ u16 f2bf(float f) {
  u32 i; __builtin_memcpy(&i, &f, 4);
  return (u16)((i + 0x7FFFu + ((i >> 16) & 1u)) >> 16);   // RNE
}
__device__ __forceinline__ f32x4 mfma16(s16x8 a, s16x8 b, f32x4 c) {
  return __builtin_amdgcn_mfma_f32_16x16x32_bf16(a, b, c, 0, 0, 0);
}
__device__ __forceinline__ void gld16(const void* g, void* l) {
  __builtin_amdgcn_global_load_lds((const __attribute__((address_space(1))) unsigned int*)g,
                                   (__attribute__((address_space(3))) unsigned int*)l, 16, 0, 0);
}

// ---------------- embedding gather ----------------
__global__ __launch_bounds__(256) void k_embed(const int* __restrict__ ids,
                                               const float* __restrict__ emb,
                                               float* __restrict__ x) {
  int t = blockIdx.x;
  const float4* src = (const float4*)(emb + (size_t)ids[t] * C_DIM);
  float4* dst = (float4*)(x + (size_t)t * C_DIM);
  dst[threadIdx.x] = src[threadIdx.x];
}

// ---------------- pad-key bias ----------------
__global__ void k_bias(const int* __restrict__ ids, float* __restrict__ bias) {
  int i = blockIdx.x * 256 + threadIdx.x;
  if (i < C_NTOK) bias[i] = (ids[i] == C_PAD) ? -1e30f : 0.0f;
}

// ---------------- rmsnorm: fp32 row -> bf16 row ----------------
__global__ __launch_bounds__(256) void k_rmsnorm(const float* __restrict__ x,
                                                 const float* __restrict__ w,
                                                 u16* __restrict__ out) {
  int row = blockIdx.x, tid = threadIdx.x;
  float4 v = ((const float4*)(x + (size_t)row * C_DIM))[tid];
  float ss = v.x * v.x + v.y * v.y + v.z * v.z + v.w * v.w;
#pragma unroll
  for (int d = 1; d < 64; d <<= 1) ss += __shfl_xor(ss, d, 64);
  __shared__ float sm[4];
  if ((tid & 63) == 0) sm[tid >> 6] = ss;
  __syncthreads();
  float tot = sm[0] + sm[1] + sm[2] + sm[3];
  float rs = 1.0f / sqrtf(tot * (1.0f / C_DIM) + 1e-5f);
  float4 wv = ((const float4*)w)[tid];
  uint2 o;
  o.x = (u32)f2bf(v.x * rs * wv.x) | ((u32)f2bf(v.y * rs * wv.y) << 16);
  o.y = (u32)f2bf(v.z * rs * wv.z) | ((u32)f2bf(v.w * rs * wv.w) << 16);
  ((uint2*)(out + (size_t)row * C_DIM))[tid] = o;
}

// ---------------- weight transpose-convert: W[K,N] f32 -> Wt[rows,K] bf16 ----------------
// ilv < 0: dst row = n.  ilv >= 0: 32-group interleave (per-wave g|u pairing):
// dst row = ((n>>5)<<6) + (n&31) + ilv   (ilv=0 gate, 32 up).
__global__ __launch_bounds__(256) void k_wT(const float* __restrict__ W,
                                            u16* __restrict__ Wt,
                                            int K, int N, size_t szW, size_t szWt,
                                            int ilv) {
  __shared__ u16 T[64][72];
  W  += (size_t)blockIdx.z * szW;
  Wt += (size_t)blockIdx.z * szWt;
  const int n0 = blockIdx.x * 64, k0 = blockIdx.y * 64;
  const int tid = threadIdx.x;
  const int r = tid >> 4, c4 = (tid & 15) * 4;
  const bool vec = ((N & 3) == 0);
#pragma unroll
  for (int it = 0; it < 4; ++it) {
    int k = k0 + r + it * 16;
    int n = n0 + c4;
    float4 v;
    if (vec && (n + 3 < N)) {
      v = *(const float4*)&W[(size_t)k * N + n];
    } else {
      v.x = (n + 0 < N) ? W[(size_t)k * N + n + 0] : 0.f;
      v.y = (n + 1 < N) ? W[(size_t)k * N + n + 1] : 0.f;
      v.z = (n + 2 < N) ? W[(size_t)k * N + n + 2] : 0.f;
      v.w = (n + 3 < N) ? W[(size_t)k * N + n + 3] : 0.f;
    }
    T[c4 + 0][r + it * 16] = f2bf(v.x);
    T[c4 + 1][r + it * 16] = f2bf(v.y);
    T[c4 + 2][r + it * 16] = f2bf(v.z);
    T[c4 + 3][r + it * 16] = f2bf(v.w);
  }
  __syncthreads();
  const int rr = tid >> 3, cc = (tid & 7) * 8;
#pragma unroll
  for (int jt = 0; jt < 2; ++jt) {
    int n = rr + jt * 32;
    int ng = n0 + n;
    int dst = (ilv < 0) ? ng : (((ng >> 5) << 6) + (ng & 31) + ilv);
    *(uint4*)&Wt[(size_t)dst * K + k0 + cc] = *(const uint4*)&T[n][cc];
  }
}

// ---------------- GEMM 128x128 (2-phase dbuf): small/odd shapes ----------------
template <int EPI, int NS>
__global__ __launch_bounds__(256) void k_gemm(const u16* __restrict__ A,
                                              const u16* __restrict__ Bt,
                                              void* __restrict__ Cp,
                                              int N, int K, int lda) {
  __shared__ u16 As[2][128 * 32];
  __shared__ u16 Bs[2][128 * 32];
  const int nx = gridDim.x;
  int lin = blockIdx.y * nx + blockIdx.x;
  const int nwg = nx * gridDim.y;
  if ((nwg & 7) == 0) lin = (lin & 7) * (nwg >> 3) + (lin >> 3);
  const int bm = (lin / nx) * 128, bn = (lin % nx) * 128;
  const int tid = threadIdx.x;
  const int lane = tid & 63, wid = tid >> 6;
  const int wr = wid >> 1, wc = wid & 1;
  const int l16 = lane & 15, lg = lane >> 4;
  const int srow = tid >> 2, scol = (tid & 3) * 8;
  const u16* Ab = A + (size_t)(bm + srow) * lda + scol;
  const u16* Bb = Bt + (size_t)(bn + srow) * K + scol;
  const int kchunk = K / NS;
  const int kb0 = blockIdx.z * kchunk, kb1 = kb0 + kchunk;
  f32x4 acc[4][4] = {};
  {
    u16* ad = &As[0][tid * 8];
    u16* bd = &Bs[0][tid * 8];
    gld16(Ab + kb0, ad);
    gld16(Ab + (size_t)64 * lda + kb0, ad + 2048);
    gld16(Bb + kb0, bd);
    gld16(Bb + (size_t)64 * K + kb0, bd + 2048);
  }
  __syncthreads();
  int cur = 0;
  for (int kb = kb0; kb < kb1; kb += 32) {
    const int nkb = kb + 32;
    if (nkb < kb1) {
      u16* ad = &As[cur ^ 1][tid * 8];
      u16* bd = &Bs[cur ^ 1][tid * 8];
      gld16(Ab + nkb, ad);
      gld16(Ab + (size_t)64 * lda + nkb, ad + 2048);
      gld16(Bb + nkb, bd);
      gld16(Bb + (size_t)64 * K + nkb, bd + 2048);
    }
    s16x8 af[4], bfr[4];
#pragma unroll
    for (int i = 0; i < 4; ++i)
      af[i] = *(const s16x8*)&As[cur][(64 * wr + 16 * i + l16) * 32 + 8 * lg];
#pragma unroll
    for (int i = 0; i < 4; ++i)
      bfr[i] = *(const s16x8*)&Bs[cur][(64 * wc + 16 * i + l16) * 32 + 8 * lg];
#pragma unroll
    for (int mi = 0; mi < 4; ++mi)
#pragma unroll
      for (int ni = 0; ni < 4; ++ni)
        acc[mi][ni] = mfma16(af[mi], bfr[ni], acc[mi][ni]);
    __syncthreads();
    cur ^= 1;
  }
#pragma unroll
  for (int mi = 0; mi < 4; ++mi)
#pragma unroll
    for (int ni = 0; ni < 4; ++ni)
#pragma unroll
      for (int r = 0; r < 4; ++r) {
        int row = bm + 64 * wr + 16 * mi + 4 * lg + r;
        int col = bn + 64 * wc + 16 * ni + l16;
        if (col >= N) continue;
        float val = acc[mi][ni][r];
        size_t off = (size_t)row * N + col;
        if (EPI == 0)      ((u16*)Cp)[off] = f2bf(val);
        else if (EPI == 1) ((float*)Cp)[off] = val;
        else if (NS == 1)  ((float*)Cp)[off] += val;
        else               unsafeAtomicAdd((float*)Cp + off, val);
      }
}

// ---------------- GEMM 256x256 8-phase (T2+T3+T4+T5): big shapes ----------------
// FULL 3-bit XOR swizzle (both-sides involution); phase-spread staging with
// counted vmcnt(2); column-major block order (B-panel L2 reuse).
// EPI 0 = bf16 store; 1 = f32 store with col<Nst guard;
// EPI 2 = fused SiLU-GU, 32-col interleaved [g|u] per wave (in-register combine).
template <int EPI>
__global__ __launch_bounds__(512, 2) void k_gemm256(const u16* __restrict__ A,
                                                    const u16* __restrict__ Bt,
                                                    void* __restrict__ Cp,
                                                    int N, int K, int lda, int Nst) {
  __shared__ u16 As[2][16384];
  __shared__ u16 Bs[2][16384];
  const int nx = gridDim.x, ny = gridDim.y;
  int lin = blockIdx.y * nx + blockIdx.x;
  const int nwg = nx * ny;
  if ((nwg & 7) == 0) lin = (lin & 7) * (nwg >> 3) + (lin >> 3);
  const int bm = (lin % ny) * 256, bn = (lin / ny) * 256;   // column-major: share B-panel
  const int tid = threadIdx.x;
  const int lane = tid & 63, wid = tid >> 6;
  const int wr = wid >> 2, wc = wid & 3;
  const int l16 = lane & 15, lg = lane >> 4;
  const int srow = tid >> 3;
  const int scol = (((tid & 7) ^ ((tid >> 3) & 7)) << 3);
  const u16* Ab = A + (size_t)(bm + srow) * lda + scol;
  const u16* Bb = Bt + (size_t)(bn + srow) * K + scol;
  const int NT = K >> 6;
  f32x4 acc[8][4] = {};

#define STG_A(b, i, kt) gld16(Ab + (size_t)((i) * 64) * lda + (kt), &As[b][(i) * 4096 + tid * 8])
#define STG_B(b, i, kt) gld16(Bb + (size_t)((i) * 64) * K + (kt), &Bs[b][(i) * 4096 + tid * 8])
#define STG_HALF(b, h, kt)                                     \
  do {                                                         \
    if ((h) == 0)      { STG_A(b, 0, kt); STG_A(b, 1, kt); }   \
    else if ((h) == 1) { STG_A(b, 2, kt); STG_A(b, 3, kt); }   \
    else if ((h) == 2) { STG_B(b, 0, kt); STG_B(b, 1, kt); }   \
    else               { STG_B(b, 2, kt); STG_B(b, 3, kt); }   \
  } while (0)
#define RD_FRAG(arr, b, row, kh)                                                     \
  (*(const s16x8*)((const char*)&arr[b][0] +                                         \
                   (((row) << 7) + (((((kh) << 2) + lg) ^ ((row) & 7)) << 4))))

  STG_HALF(0, 0, 0); STG_HALF(0, 1, 0); STG_HALF(0, 2, 0); STG_HALF(0, 3, 0);
  int c = 0;
  for (int j = 0; j < NT; ++j) {
    const int ktn = (j + 1) << 6;
    const bool pf = (j + 1 < NT);
    s16x8 af[4][2], bfr[4][2];
    // ---- phase 0 (mh=0, nh=0): entry wait + barrier, then reads ----
    if (pf) { STG_HALF(c ^ 1, 0, ktn); asm volatile("s_waitcnt vmcnt(2)" ::: "memory"); }
    else    { asm volatile("s_waitcnt vmcnt(0)" ::: "memory"); }
    __builtin_amdgcn_s_barrier();
    __builtin_amdgcn_sched_barrier(0);
#pragma unroll
    for (int i = 0; i < 4; ++i) {
      int row = wr * 128 + i * 16 + l16;
      af[i][0] = RD_FRAG(As, c, row, 0);
      af[i][1] = RD_FRAG(As, c, row, 1);
    }
#pragma unroll
    for (int n = 0; n < 2; ++n) {
      int row = wc * 64 + n * 16 + l16;
      bfr[n][0] = RD_FRAG(Bs, c, row, 0);
      bfr[n][1] = RD_FRAG(Bs, c, row, 1);
    }
    asm volatile("s_waitcnt lgkmcnt(0)" ::: "memory");
    __builtin_amdgcn_sched_barrier(0);
    __builtin_amdgcn_s_setprio(1);
#pragma unroll
    for (int i = 0; i < 4; ++i)
#pragma unroll
      for (int n = 0; n < 2; ++n) {
        acc[i][n] = mfma16(af[i][0], bfr[n][0], acc[i][n]);
        acc[i][n] = mfma16(af[i][1], bfr[n][1], acc[i][n]);
      }
    __builtin_amdgcn_s_setprio(0);
    __builtin_amdgcn_s_barrier();
    // ---- phase 1 (mh=0, nh=1) ----
#pragma unroll
    for (int n = 0; n < 2; ++n) {
      int row = wc * 64 + (2 + n) * 16 + l16;
      bfr[2 + n][0] = RD_FRAG(Bs, c, row, 0);
      bfr[2 + n][1] = RD_FRAG(Bs, c, row, 1);
    }
    if (pf) STG_HALF(c ^ 1, 1, ktn);
    __builtin_amdgcn_s_barrier();
    asm volatile("s_waitcnt lgkmcnt(0)" ::: "memory");
    __builtin_amdgcn_sched_barrier(0);
    __builtin_amdgcn_s_setprio(1);
#pragma unroll
    for (int i = 0; i < 4; ++i)
#pragma unroll
      for (int n = 0; n < 2; ++n) {
        acc[i][2 + n] = mfma16(af[i][0], bfr[2 + n][0], acc[i][2 + n]);
        acc[i][2 + n] = mfma16(af[i][1], bfr[2 + n][1], acc[i][2 + n]);
      }
    __builtin_amdgcn_s_setprio(0);
    __builtin_amdgcn_s_barrier();
    // ---- phase 2 (mh=1, nh=0) ----
#pragma unroll
    for (int i = 0; i < 4; ++i) {
      int row = wr * 128 + (4 + i) * 16 + l16;
      af[i][0] = RD_FRAG(As, c, row, 0);
      af[i][1] = RD_FRAG(As, c, row, 1);
    }
    if (pf) STG_HALF(c ^ 1, 2, ktn);
    __builtin_amdgcn_s_barrier();
    asm volatile("s_waitcnt lgkmcnt(0)" ::: "memory");
    __builtin_amdgcn_sched_barrier(0);
    __builtin_amdgcn_s_setprio(1);
#pragma unroll
    for (int i = 0; i < 4; ++i)
#pragma unroll
      for (int n = 0; n < 2; ++n) {
        acc[4 + i][n] = mfma16(af[i][0], bfr[n][0], acc[4 + i][n]);
        acc[4 + i][n] = mfma16(af[i][1], bfr[n][1], acc[4 + i][n]);
      }
    __builtin_amdgcn_s_setprio(0);
    __builtin_amdgcn_s_barrier();
    // ---- phase 3 (mh=1, nh=1) ----
    if (pf) STG_HALF(c ^ 1, 3, ktn);
    __builtin_amdgcn_s_barrier();
    __builtin_amdgcn_s_setprio(1);
#pragma unroll
    for (int i = 0; i < 4; ++i)
#pragma unroll
      for (int n = 0; n < 2; ++n) {
        acc[4 + i][2 + n] = mfma16(af[i][0], bfr[2 + n][0], acc[4 + i][2 + n]);
        acc[4 + i][2 + n] = mfma16(af[i][1], bfr[2 + n][1], acc[4 + i][2 + n]);
      }
    __builtin_amdgcn_s_setprio(0);
    __builtin_amdgcn_s_barrier();
    c ^= 1;
  }
#undef STG_A
#undef STG_B
#undef STG_HALF
#undef RD_FRAG
  if (EPI == 2) {
    // in-register SiLU-GU: acc[.][ni] = g, acc[.][ni+2] = u of same ff-col.
#pragma unroll
    for (int mi = 0; mi < 8; ++mi)
#pragma unroll
      for (int ni = 0; ni < 2; ++ni)
#pragma unroll
        for (int r = 0; r < 4; ++r) {
          float g = acc[mi][ni][r];
          float u = acc[mi][ni + 2][r];
          float s = g / (1.0f + __expf(-g));
          int row = bm + wr * 128 + mi * 16 + 4 * lg + r;
          int col = (bn >> 1) + wc * 32 + ni * 16 + l16;
          ((u16*)Cp)[(size_t)row * Nst + col] = f2bf(s * u);
        }
    return;
  }
#pragma unroll
  for (int mi = 0; mi < 8; ++mi)
#pragma unroll
    for (int ni = 0; ni < 4; ++ni)
#pragma unroll
      for (int r = 0; r < 4; ++r) {
        int row = bm + wr * 128 + mi * 16 + 4 * lg + r;
        int col = bn + wc * 64 + ni * 16 + l16;
        float val = acc[mi][ni][r];
        if (EPI == 0) {
          ((u16*)Cp)[(size_t)row * N + col] = f2bf(val);
        } else {
          if (col < Nst) ((float*)Cp)[(size_t)row * Nst + col] = val;
        }
      }
}

// ---------------- RoPE in-place, q+k heads in one launch (24 virtual heads) ----------------
__global__ void k_rope(u16* __restrict__ buf) {
  int idx = blockIdx.x * 256 + threadIdx.x;   // C_NTOK * 24 * 16 total
  int j = idx & 15;
  int h = (idx >> 4) % 24;
  int t = idx / (16 * 24);
  int pos = t & (C_S - 1);
  const float L = 13.122363377404328f;   // ln(500000)
  float inv0 = expf(-(float)(4 * j)     * (1.0f / C_HD) * L);
  float inv1 = expf(-(float)(4 * j + 2) * (1.0f / C_HD) * L);
  float a0 = (float)pos * inv0, a1 = (float)pos * inv1;
  float c0 = cosf(a0), s0 = sinf(a0), c1 = cosf(a1), s1 = sinf(a1);
  int hoff = (h < 16) ? h * C_HD : 1024 + (h - 16) * C_HD;
  u16* pp = buf + (size_t)t * 2048 + hoff + 2 * j;
  u32 lo = *(u32*)pp;
  u32 hi = *(u32*)(pp + 32);
  float x0a = bf2f((u16)lo), x0b = bf2f((u16)(lo >> 16));
  float x1a = bf2f((u16)hi), x1b = bf2f((u16)(hi >> 16));
  *(u32*)pp        = (u32)f2bf(x0a * c0 - x1a * s0) | ((u32)f2bf(x0b * c1 - x1b * s1) << 16);
  *(u32*)(pp + 32) = (u32)f2bf(x1a * c0 + x0a * s0) | ((u32)f2bf(x1b * c1 + x0b * s1) << 16);
}

// ---------------- fragment-order pack of K and V per 64-key tile (V via LDS transpose) ----
__global__ __launch_bounds__(256) void k_pack(const u16* __restrict__ qkv,
                                              u16* __restrict__ KP,
                                              u16* __restrict__ VP) {
  const int t = blockIdx.x, kvh = blockIdx.y, b = blockIdx.z;
  const int tid = threadIdx.x;
  __shared__ u16 T[64][72];
  {  // stage V tile [64 s][64 hd] coalesced
    const int r = tid >> 2, q = tid & 3;
    const u16* src = qkv + ((size_t)(b * C_S + 64 * t + r)) * 2048 + 1536 + kvh * C_HD + 16 * q;
    *(uint4*)&T[r][16 * q]     = *(const uint4*)src;
    *(uint4*)&T[r][16 * q + 8] = *(const uint4*)(src + 8);
  }
  __syncthreads();
  const int lane = tid & 63, i4 = tid >> 6;
  const int l16 = lane & 15, lg = lane >> 4;
  const size_t obase = (((size_t)((b * 8 + kvh) * 32 + t)) * 8) * 512 + (size_t)lane * 8;
#pragma unroll
  for (int r = 0; r < 2; ++r) {
    int inst = i4 + 4 * r;
    int jt = inst >> 1, h = inst & 1;
    const u16* ks = qkv + (size_t)(b * C_S + 64 * t + 16 * jt + l16) * 2048
                    + 1024 + kvh * C_HD + 32 * h + 8 * lg;
    *(uint4*)(KP + obase + (size_t)inst * 512) = *(const uint4*)ks;
    u16 vtmp[8];
#pragma unroll
    for (int j = 0; j < 8; ++j) vtmp[j] = T[32 * h + 8 * lg + j][16 * jt + l16];
    *(uint4*)(VP + obase + (size_t)inst * 512) = *(uint4*)vtmp;
  }
}

// ---------------- flash attention (paired) with fragment-packed K/V ----------
// Mask only the diagonal (last) tile: for t < nt-1, kt+63 < q0 <= qrow always.
// Tree-reduced max/sum (per-jt partials); exact skip-rescale when no lane's max grew.
__global__ __launch_bounds__(64) void k_attn(const u16* __restrict__ qkv,
                                             const u16* __restrict__ KP,
                                             const u16* __restrict__ VP,
                                             const float* __restrict__ bias,
                                             u16* __restrict__ o) {
  const int qp = blockIdx.x, h = blockIdx.y, b = blockIdx.z;
  const int kvh = h >> 1;
  const int lane = threadIdx.x;
  const int l16 = lane & 15, lg = lane >> 4;
  __shared__ u16 P[16][72];
  const float* biasb = bias + b * C_S;
  const u16* kpb = KP + ((size_t)((b * 8 + kvh) * 32) * 8) * 512 + (size_t)lane * 8;
  const u16* vpb = VP + ((size_t)((b * 8 + kvh) * 32) * 8) * 512 + (size_t)lane * 8;
#pragma unroll
  for (int half = 0; half < 2; ++half) {
    const int qt = half ? (127 - qp) : qp;
    const int q0 = qt * 16;
    const int qrow = q0 + l16;
    const u16* qbase = qkv + (size_t)(b * C_S + qrow) * 2048 + h * C_HD + 8 * lg;
    s16x8 qf0 = *(const s16x8*)qbase;
    s16x8 qf1 = *(const s16x8*)(qbase + 32);
    float m = -1e30f, lsum = 0.f;
    f32x4 accO[4];
#pragma unroll
    for (int f = 0; f < 4; ++f) accO[f] = (f32x4){0.f, 0.f, 0.f, 0.f};
    const int nt = (q0 + 16 + 63) >> 6;
    s16x8 kf[8], vf[8];
#pragma unroll
    for (int i = 0; i < 8; ++i) kf[i] = *(const s16x8*)(kpb + (size_t)i * 512);
#pragma unroll
    for (int i = 0; i < 8; ++i) vf[i] = *(const s16x8*)(vpb + (size_t)i * 512);
    for (int t = 0; t < nt; ++t) {
      const int kt = t * 64;
      f32x4 sc[4];
#pragma unroll
      for (int jt = 0; jt < 4; ++jt) sc[jt] = (f32x4){0.f, 0.f, 0.f, 0.f};
#pragma unroll
      for (int jt = 0; jt < 4; ++jt) {
        sc[jt] = mfma16(kf[2 * jt],     qf0, sc[jt]);
        sc[jt] = mfma16(kf[2 * jt + 1], qf1, sc[jt]);
      }
      if (t + 1 < nt) {
        const u16* kn = kpb + (size_t)(t + 1) * 8 * 512;
#pragma unroll
        for (int i = 0; i < 8; ++i) kf[i] = *(const s16x8*)(kn + (size_t)i * 512);
      }
      float mt4[4];
      if (t == nt - 1) {   // diagonal tile: causal mask needed
#pragma unroll
        for (int jt = 0; jt < 4; ++jt) {
          float4 bb = *(const float4*)&biasb[kt + 16 * jt + 4 * lg];
          int kv0 = kt + 16 * jt + 4 * lg;
          const float* bp = (const float*)&bb;
          float mj = -1e30f;
#pragma unroll
          for (int r = 0; r < 4; ++r) {
            float val = sc[jt][r] * 0.125f + bp[r];
            if (kv0 + r > qrow) val = -1e30f;
            sc[jt][r] = val;
            mj = fmaxf(mj, val);
          }
          mt4[jt] = mj;
        }
      } else {             // interior tile: no causal masking possible
#pragma unroll
        for (int jt = 0; jt < 4; ++jt) {
          float4 bb = *(const float4*)&biasb[kt + 16 * jt + 4 * lg];
          const float* bp = (const float*)&bb;
          float mj = -1e30f;
#pragma unroll
          for (int r = 0; r < 4; ++r) {
            float val = sc[jt][r] * 0.125f + bp[r];
            sc[jt][r] = val;
            mj = fmaxf(mj, val);
          }
          mt4[jt] = mj;
        }
      }
      float mt = fmaxf(fmaxf(mt4[0], mt4[1]), fmaxf(mt4[2], mt4[3]));
      mt = fmaxf(mt, __shfl_xor(mt, 16, 64));
      mt = fmaxf(mt, __shfl_xor(mt, 32, 64));
      if (__all(mt <= m)) {   // exact skip: cc would be 1
        float ps4[4];
#pragma unroll
        for (int jt = 0; jt < 4; ++jt) {
          float pj = 0.f;
#pragma unroll
          for (int r = 0; r < 4; ++r) {
            float pv = __expf(sc[jt][r] - m);
            sc[jt][r] = pv;
            pj += pv;
          }
          ps4[jt] = pj;
        }
        float ps = (ps4[0] + ps4[1]) + (ps4[2] + ps4[3]);
        ps += __shfl_xor(ps, 16, 64);
        ps += __shfl_xor(ps, 32, 64);
        lsum += ps;
      } else {
        float mn = fmaxf(m, mt);
        float cc = __expf(m - mn);
        m = mn;
        float ps4[4];
#pragma unroll
        for (int jt = 0; jt < 4; ++jt) {
          float pj = 0.f;
#pragma unroll
          for (int r = 0; r < 4; ++r) {
            float pv = __expf(sc[jt][r] - m);
            sc[jt][r] = pv;
            pj += pv;
          }
          ps4[jt] = pj;
        }
        float ps = (ps4[0] + ps4[1]) + (ps4[2] + ps4[3]);
        ps += __shfl_xor(ps, 16, 64);
        ps += __shfl_xor(ps, 32, 64);
        lsum = lsum * cc + ps;
#pragma unroll
        for (int f = 0; f < 4; ++f)
#pragma unroll
          for (int r = 0; r < 4; ++r) accO[f][r] *= cc;
      }
#pragma unroll
      for (int jt = 0; jt < 4; ++jt) {
        uint2 w;
        w.x = (u32)f2bf(sc[jt][0]) | ((u32)f2bf(sc[jt][1]) << 16);
        w.y = (u32)f2bf(sc[jt][2]) | ((u32)f2bf(sc[jt][3]) << 16);
        *(uint2*)&P[l16][16 * jt + 4 * lg] = w;
      }
      asm volatile("s_waitcnt lgkmcnt(0)" ::: "memory");   // DS writes retired
      __builtin_amdgcn_sched_barrier(0);                   // rule 18: pin MFMA below
      s16x8 pf0 = *(const s16x8*)&P[l16][8 * lg];
      s16x8 pf1 = *(const s16x8*)&P[l16][32 + 8 * lg];
#pragma unroll
      for (int f = 0; f < 4; ++f) {
        accO[f] = mfma16(vf[2 * f],     pf0, accO[f]);
        accO[f] = mfma16(vf[2 * f + 1], pf1, accO[f]);
      }
      if (t + 1 < nt) {
        const u16* vn = vpb + (size_t)(t + 1) * 8 * 512;
#pragma unroll
        for (int i = 0; i < 8; ++i) vf[i] = *(const s16x8*)(vn + (size_t)i * 512);
      }
    }
    float linv = 1.0f / lsum;
    u16* ob = o + ((size_t)(b * C_S + qrow)) * 1024 + h * C_HD + 4 * lg;
#pragma unroll
    for (int f = 0; f < 4; ++f) {
      uint2 w;
      w.x = (u32)f2bf(accO[f][0] * linv) | ((u32)f2bf(accO[f][1] * linv) << 16);
      w.y = (u32)f2bf(accO[f][2] * linv) | ((u32)f2bf(accO[f][3] * linv) << 16);
      *(uint2*)(ob + 16 * f) = w;
    }
  }
}

extern "C" void kernel_launch(void* const* d_in, const int* in_sizes, int n_in,
                              void* d_out, int out_size, void* d_ws, size_t ws_size,
                              hipStream_t stream) {
  const int*   ids  = (const int*)d_in[0];
  const float* emb  = (const float*)d_in[1];
  const float* Wq   = (const float*)d_in[2];
  const float* Wk   = (const float*)d_in[3];
  const float* Wv   = (const float*)d_in[4];
  const float* Wo   = (const float*)d_in[5];
  const float* Wg   = (const float*)d_in[6];
  const float* Wu   = (const float*)d_in[7];
  const float* Wd   = (const float*)d_in[8];
  const float* anw  = (const float*)d_in[9];
  const float* fnw  = (const float*)d_in[10];
  const float* finw = (const float*)d_in[11];
  const float* lmh  = (const float*)d_in[12];

  char* p = (char*)d_ws;
  float* x  = (float*)p; p += (size_t)C_NTOK * C_DIM * 4;
  u16* hn   = (u16*)p;   p += (size_t)C_NTOK * C_DIM * 2;
  u16* qkv  = (u16*)p;   p += (size_t)C_NTOK * 2048 * 2;
  u16* vtb  = (u16*)p;   p += (size_t)C_NTOK * C_NKVH * C_HD * 2;   // unused (kept for layout)
  u16* ao   = (u16*)p;   p += (size_t)C_NTOK * C_NH * C_HD * 2;
  u16* gu   = (u16*)p;   p += (size_t)C_NTOK * 2 * C_FF * 2;        // gu now [4096][4096] bf16
  u16* wT   = (u16*)p;   p += (size_t)8192 * 1024 * 2;
  float* bias = (float*)p; p += (size_t)C_NTOK * 4;
  u16* KP   = (u16*)p;   p += (size_t)C_B * 8 * 32 * 8 * 512 * 2;   // 4MB
  u16* VP   = (u16*)p;   p += (size_t)C_B * 8 * 32 * 8 * 512 * 2;   // 4MB
  u16* wTall = (u16*)p;
  (void)vtb;

  const size_t M1 = 1024 * 1024;               // 1M elems
  const size_t O_qkv = 0;                      // L x 2M (q@0, k@+1M, v@+1.5M)
  const size_t O_wo  = O_qkv + 16 * M1;        // L x 1M
  const size_t O_gu  = O_wo + 8 * M1;          // L x 8M (32-row interleaved g|u)
  const size_t O_wd  = O_gu + 64 * M1;         // L x 4M
  const size_t O_lmh = O_wd + 32 * M1;         // 4M
  const size_t wTall_elems = O_lmh + 4 * M1;   // 124M elems = 248MB
  const size_t needed = ((char*)wTall - (char*)d_ws) + wTall_elems * 2;
  const bool big = ws_size >= needed;

  k_embed<<<C_NTOK, 256, 0, stream>>>(ids, emb, x);
  k_bias<<<C_NTOK / 256, 256, 0, stream>>>(ids, bias);

  if (big) {
    k_wT<<<dim3(16, 16, 8), 256, 0, stream>>>(Wq, wTall + O_qkv, C_DIM, 1024, M1, 2 * M1, -1);
    k_wT<<<dim3(8, 16, 8), 256, 0, stream>>>(Wk, wTall + O_qkv + M1, C_DIM, 512, M1 / 2, 2 * M1, -1);
    k_wT<<<dim3(8, 16, 8), 256, 0, stream>>>(Wv, wTall + O_qkv + M1 + M1 / 2, C_DIM, 512, M1 / 2, 2 * M1, -1);
    k_wT<<<dim3(16, 16, 8), 256, 0, stream>>>(Wo, wTall + O_wo, 1024, C_DIM, M1, M1, -1);
    k_wT<<<dim3(64, 16, 8), 256, 0, stream>>>(Wg, wTall + O_gu, C_DIM, C_FF, 4 * M1, 8 * M1, 0);
    k_wT<<<dim3(64, 16, 8), 256, 0, stream>>>(Wu, wTall + O_gu, C_DIM, C_FF, 4 * M1, 8 * M1, 32);
    k_wT<<<dim3(16, 64, 8), 256, 0, stream>>>(Wd, wTall + O_wd, C_FF, C_DIM, 4 * M1, 4 * M1, -1);
    k_wT<<<dim3(64, 16, 1), 256, 0, stream>>>(lmh, wTall + O_lmh, C_DIM, C_V, 0, 0, -1);
  }

  for (int l = 0; l < C_NL; ++l) {
    k_rmsnorm<<<C_NTOK, 256, 0, stream>>>(x, anw + (size_t)l * C_DIM, hn);
    const u16* qkvT;
    if (big) {
      qkvT = wTall + O_qkv + (size_t)l * 2 * M1;
    } else {
      k_wT<<<dim3(16, 16), 256, 0, stream>>>(Wq + (size_t)l * M1, wT, C_DIM, 1024, 0, 0, -1);
      k_wT<<<dim3(8, 16), 256, 0, stream>>>(Wk + (size_t)l * M1 / 2, wT + M1, C_DIM, 512, 0, 0, -1);
      k_wT<<<dim3(8, 16), 256, 0, stream>>>(Wv + (size_t)l * M1 / 2, wT + M1 + M1 / 2, C_DIM, 512, 0, 0, -1);
      qkvT = wT;
    }
    k_gemm<0, 1><<<dim3(16, 32), 256, 0, stream>>>(hn, qkvT, qkv, 2048, C_DIM, C_DIM);
    k_rope<<<C_NTOK * 24 * 16 / 256, 256, 0, stream>>>(qkv);
    k_pack<<<dim3(32, C_NKVH, C_B), 256, 0, stream>>>(qkv, KP, VP);
    k_attn<<<dim3(64, C_NH, C_B), 64, 0, stream>>>(qkv, KP, VP, bias, ao);
    const u16* woT;
    if (big) {
      woT = wTall + O_wo + (size_t)l * M1;
    } else {
      k_wT<<<dim3(16, 16), 256, 0, stream>>>(Wo + (size_t)l * M1, wT, 1024, C_DIM, 0, 0, -1);
      woT = wT;
    }
    k_gemm<2, 2><<<dim3(8, 32, 2), 256, 0, stream>>>(ao, woT, x, C_DIM, 1024, 1024);
    k_rmsnorm<<<C_NTOK, 256, 0, stream>>>(x, fnw + (size_t)l * C_DIM, hn);
    const u16* guT;
    if (big) {
      guT = wTall + O_gu + (size_t)l * 8 * M1;
    } else {
      k_wT<<<dim3(64, 16), 256, 0, stream>>>(Wg + (size_t)l * 4 * M1, wT, C_DIM, C_FF, 0, 0, 0);
      k_wT<<<dim3(64, 16), 256, 0, stream>>>(Wu + (size_t)l * 4 * M1, wT, C_DIM, C_FF, 0, 0, 32);
      guT = wT;
    }
    k_gemm256<2><<<dim3(32, 16), 512, 0, stream>>>(hn, guT, gu, 8192, C_DIM, C_DIM, 4096);
    const u16* wdT;
    if (big) {
      wdT = wTall + O_wd + (size_t)l * 4 * M1;
    } else {
      k_wT<<<dim3(16, 64), 256, 0, stream>>>(Wd + (size_t)l * 4 * M1, wT, C_FF, C_DIM, 0, 0, -1);
      wdT = wT;
    }
    k_gemm<2, 4><<<dim3(8, 32, 4), 256, 0, stream>>>(gu, wdT, x, C_DIM, C_FF, 4096);
  }
  k_rmsnorm<<<C_NTOK, 256, 0, stream>>>(x, finw, hn);
  const u16* lmhT;
  if (big) {
    lmhT = wTall + O_lmh;
  } else {
    k_wT<<<dim3(64, 16), 256, 0, stream>>>(lmh, wT, C_DIM, C_V, 0, 0, -1);
    lmhT = wT;
  }
  k_gemm256<1><<<dim3(16, 16), 512, 0, stream>>>(hn, lmhT, d_out, 4096, C_DIM, C_DIM, C_V);
}

// Round 20
// 2692.476 us; speedup vs baseline: 1.0096x; 1.0096x over previous
//
#include <hip/hip_runtime.h>

constexpr int C_NTOK = 4096;   // B*S
constexpr int C_DIM  = 1024;
constexpr int C_NL   = 8;
constexpr int C_NH   = 16;
constexpr int C_NKVH = 8;
constexpr int C_FF   = 4096;
constexpr int C_HD   = 64;
constexpr int C_B    = 2;
constexpr int C_S    = 2048;
constexpr int C_V    = 4054;
constexpr int C_PAD  = 4053;

typedef unsigned short u16;
typedef unsigned int   u32;
typedef __attribute__((ext_vector_type(4))) float f32x4;
typedef __attribute__((ext_vector_type(8))) short s16x8;

__device__ __forceinline__ float bf2f(u16 u) {
  u32 i = ((u32)u) << 16; float f; __builtin_memcpy(&f, &i, 4); return f;
}
__device__ __forceinline__ u16 f2bf(float f) {
  u32 i; __builtin_memcpy(&i, &f, 4);
  return (u16)((i + 0x7FFFu + ((i >> 16) & 1u)) >> 16);   // RNE
}
__device__ __forceinline__ f32x4 mfma16(s16x8 a, s16x8 b, f32x4 c) {
  return __builtin_amdgcn_mfma_f32_16x16x32_bf16(a, b, c, 0, 0, 0);
}
__device__ __forceinline__ void gld16(const void* g, void* l) {
  __builtin_amdgcn_global_load_lds((const __attribute__((address_space(1))) unsigned int*)g,
                                   (__attribute__((address_space(3))) unsigned int*)l, 16, 0, 0);
}

// ---------------- embedding gather ----------------
__global__ __launch_bounds__(256) void k_embed(const int* __restrict__ ids,
                                               const float* __restrict__ emb,
                                               float* __restrict__ x) {
  int t = blockIdx.x;
  const float4* src = (const float4*)(emb + (size_t)ids[t] * C_DIM);
  float4* dst = (float4*)(x + (size_t)t * C_DIM);
  dst[threadIdx.x] = src[threadIdx.x];
}

// ---------------- pad-key bias ----------------
__global__ void k_bias(const int* __restrict__ ids, float* __restrict__ bias) {
  int i = blockIdx.x * 256 + threadIdx.x;
  if (i < C_NTOK) bias[i] = (ids[i] == C_PAD) ? -1e30f : 0.0f;
}

// ---------------- rmsnorm: fp32 row -> bf16 row ----------------
__global__ __launch_bounds__(256) void k_rmsnorm(const float* __restrict__ x,
                                                 const float* __restrict__ w,
                                                 u16* __restrict__ out) {
  int row = blockIdx.x, tid = threadIdx.x;
  float4 v = ((const float4*)(x + (size_t)row * C_DIM))[tid];
  float ss = v.x * v.x + v.y * v.y + v.z * v.z + v.w * v.w;
#pragma unroll
  for (int d = 1; d < 64; d <<= 1) ss += __shfl_xor(ss, d, 64);
  __shared__ float sm[4];
  if ((tid & 63) == 0) sm[tid >> 6] = ss;
  __syncthreads();
  float tot = sm[0] + sm[1] + sm[2] + sm[3];
  float rs = 1.0f / sqrtf(tot * (1.0f / C_DIM) + 1e-5f);
  float4 wv = ((const float4*)w)[tid];
  uint2 o;
  o.x = (u32)f2bf(v.x * rs * wv.x) | ((u32)f2bf(v.y * rs * wv.y) << 16);
  o.y = (u32)f2bf(v.z * rs * wv.z) | ((u32)f2bf(v.w * rs * wv.w) << 16);
  ((uint2*)(out + (size_t)row * C_DIM))[tid] = o;
}

// ---------------- weight transpose-convert: W[K,N] f32 -> Wt[rows,K] bf16 ----------------
// ilv < 0: dst row = n.  ilv >= 0: 32-group interleave (per-wave g|u pairing):
// dst row = ((n>>5)<<6) + (n&31) + ilv   (ilv=0 gate, 32 up).
__global__ __launch_bounds__(256) void k_wT(const float* __restrict__ W,
                                            u16* __restrict__ Wt,
                                            int K, int N, size_t szW, size_t szWt,
                                            int ilv) {
  __shared__ u16 T[64][72];
  W  += (size_t)blockIdx.z * szW;
  Wt += (size_t)blockIdx.z * szWt;
  const int n0 = blockIdx.x * 64, k0 = blockIdx.y * 64;
  const int tid = threadIdx.x;
  const int r = tid >> 4, c4 = (tid & 15) * 4;
  const bool vec = ((N & 3) == 0);
#pragma unroll
  for (int it = 0; it < 4; ++it) {
    int k = k0 + r + it * 16;
    int n = n0 + c4;
    float4 v;
    if (vec && (n + 3 < N)) {
      v = *(const float4*)&W[(size_t)k * N + n];
    } else {
      v.x = (n + 0 < N) ? W[(size_t)k * N + n + 0] : 0.f;
      v.y = (n + 1 < N) ? W[(size_t)k * N + n + 1] : 0.f;
      v.z = (n + 2 < N) ? W[(size_t)k * N + n + 2] : 0.f;
      v.w = (n + 3 < N) ? W[(size_t)k * N + n + 3] : 0.f;
    }
    T[c4 + 0][r + it * 16] = f2bf(v.x);
    T[c4 + 1][r + it * 16] = f2bf(v.y);
    T[c4 + 2][r + it * 16] = f2bf(v.z);
    T[c4 + 3][r + it * 16] = f2bf(v.w);
  }
  __syncthreads();
  const int rr = tid >> 3, cc = (tid & 7) * 8;
#pragma unroll
  for (int jt = 0; jt < 2; ++jt) {
    int n = rr + jt * 32;
    int ng = n0 + n;
    int dst = (ilv < 0) ? ng : (((ng >> 5) << 6) + (ng & 31) + ilv);
    *(uint4*)&Wt[(size_t)dst * K + k0 + cc] = *(const uint4*)&T[n][cc];
  }
}

// ---------------- GEMM 128x128 (2-phase dbuf): small/odd shapes ----------------
template <int EPI, int NS>
__global__ __launch_bounds__(256) void k_gemm(const u16* __restrict__ A,
                                              const u16* __restrict__ Bt,
                                              void* __restrict__ Cp,
                                              int N, int K, int lda) {
  __shared__ u16 As[2][128 * 32];
  __shared__ u16 Bs[2][128 * 32];
  const int nx = gridDim.x;
  int lin = blockIdx.y * nx + blockIdx.x;
  const int nwg = nx * gridDim.y;
  if ((nwg & 7) == 0) lin = (lin & 7) * (nwg >> 3) + (lin >> 3);
  const int bm = (lin / nx) * 128, bn = (lin % nx) * 128;
  const int tid = threadIdx.x;
  const int lane = tid & 63, wid = tid >> 6;
  const int wr = wid >> 1, wc = wid & 1;
  const int l16 = lane & 15, lg = lane >> 4;
  const int srow = tid >> 2, scol = (tid & 3) * 8;
  const u16* Ab = A + (size_t)(bm + srow) * lda + scol;
  const u16* Bb = Bt + (size_t)(bn + srow) * K + scol;
  const int kchunk = K / NS;
  const int kb0 = blockIdx.z * kchunk, kb1 = kb0 + kchunk;
  f32x4 acc[4][4] = {};
  {
    u16* ad = &As[0][tid * 8];
    u16* bd = &Bs[0][tid * 8];
    gld16(Ab + kb0, ad);
    gld16(Ab + (size_t)64 * lda + kb0, ad + 2048);
    gld16(Bb + kb0, bd);
    gld16(Bb + (size_t)64 * K + kb0, bd + 2048);
  }
  __syncthreads();
  int cur = 0;
  for (int kb = kb0; kb < kb1; kb += 32) {
    const int nkb = kb + 32;
    if (nkb < kb1) {
      u16* ad = &As[cur ^ 1][tid * 8];
      u16* bd = &Bs[cur ^ 1][tid * 8];
      gld16(Ab + nkb, ad);
      gld16(Ab + (size_t)64 * lda + nkb, ad + 2048);
      gld16(Bb + nkb, bd);
      gld16(Bb + (size_t)64 * K + nkb, bd + 2048);
    }
    s16x8 af[4], bfr[4];
#pragma unroll
    for (int i = 0; i < 4; ++i)
      af[i] = *(const s16x8*)&As[cur][(64 * wr + 16 * i + l16) * 32 + 8 * lg];
#pragma unroll
    for (int i = 0; i < 4; ++i)
      bfr[i] = *(const s16x8*)&Bs[cur][(64 * wc + 16 * i + l16) * 32 + 8 * lg];
#pragma unroll
    for (int mi = 0; mi < 4; ++mi)
#pragma unroll
      for (int ni = 0; ni < 4; ++ni)
        acc[mi][ni] = mfma16(af[mi], bfr[ni], acc[mi][ni]);
    __syncthreads();
    cur ^= 1;
  }
#pragma unroll
  for (int mi = 0; mi < 4; ++mi)
#pragma unroll
    for (int ni = 0; ni < 4; ++ni)
#pragma unroll
      for (int r = 0; r < 4; ++r) {
        int row = bm + 64 * wr + 16 * mi + 4 * lg + r;
        int col = bn + 64 * wc + 16 * ni + l16;
        if (col >= N) continue;
        float val = acc[mi][ni][r];
        size_t off = (size_t)row * N + col;
        if (EPI == 0)      ((u16*)Cp)[off] = f2bf(val);
        else if (EPI == 1) ((float*)Cp)[off] = val;
        else if (NS == 1)  ((float*)Cp)[off] += val;
        else               unsafeAtomicAdd((float*)Cp + off, val);
      }
}

// ---------------- GEMM 256x256 8-phase (T2+T3+T4+T5): big shapes ----------------
// FULL 3-bit XOR swizzle (both-sides involution); column-major block order.
// Consumption-ordered staging: per tile issue {A0,A2}@P0, {B0,B1}@P1, {B2,B3}@P2,
// {A1,A3}@P3 with counted waits vmcnt(4)@P0 / vmcnt(6)@P2 -> every load gets
// >=3 phases of latency slack (A1/A3 only consumed at P2 of the next iter).
// EPI 0 = bf16 store; 1 = f32 store with col<Nst guard;
// EPI 2 = fused SiLU-GU, 32-col interleaved [g|u] per wave (in-register combine).
template <int EPI>
__global__ __launch_bounds__(512, 2) void k_gemm256(const u16* __restrict__ A,
                                                    const u16* __restrict__ Bt,
                                                    void* __restrict__ Cp,
                                                    int N, int K, int lda, int Nst) {
  __shared__ u16 As[2][16384];
  __shared__ u16 Bs[2][16384];
  const int nx = gridDim.x, ny = gridDim.y;
  int lin = blockIdx.y * nx + blockIdx.x;
  const int nwg = nx * ny;
  if ((nwg & 7) == 0) lin = (lin & 7) * (nwg >> 3) + (lin >> 3);
  const int bm = (lin % ny) * 256, bn = (lin / ny) * 256;   // column-major: share B-panel
  const int tid = threadIdx.x;
  const int lane = tid & 63, wid = tid >> 6;
  const int wr = wid >> 2, wc = wid & 3;
  const int l16 = lane & 15, lg = lane >> 4;
  const int srow = tid >> 3;
  const int scol = (((tid & 7) ^ ((tid >> 3) & 7)) << 3);
  const u16* Ab = A + (size_t)(bm + srow) * lda + scol;
  const u16* Bb = Bt + (size_t)(bn + srow) * K + scol;
  const int NT = K >> 6;
  f32x4 acc[8][4] = {};

#define STG_A(b, i, kt) gld16(Ab + (size_t)((i) * 64) * lda + (kt), &As[b][(i) * 4096 + tid * 8])
#define STG_B(b, i, kt) gld16(Bb + (size_t)((i) * 64) * K + (kt), &Bs[b][(i) * 4096 + tid * 8])
#define RD_FRAG(arr, b, row, kh)                                                     \
  (*(const s16x8*)((const char*)&arr[b][0] +                                         \
                   (((row) << 7) + (((((kh) << 2) + lg) ^ ((row) & 7)) << 4))))

  // prologue: tile 0 staged in consumption-FIFO order A0,A2,B0,B1,B2,B3,A1,A3
  STG_A(0, 0, 0); STG_A(0, 2, 0);
  STG_B(0, 0, 0); STG_B(0, 1, 0);
  STG_B(0, 2, 0); STG_B(0, 3, 0);
  STG_A(0, 1, 0); STG_A(0, 3, 0);
  int c = 0;
  for (int j = 0; j < NT; ++j) {
    const int ktn = (j + 1) << 6;
    const bool pf = (j + 1 < NT);
    s16x8 af[4][2], bfr[4][2];
    // ---- phase 0 (mh=0, nh=0): issue {A0,A2}, wait tile-j A0,A2,B0..B3 ----
    if (pf) { STG_A(c ^ 1, 0, ktn); STG_A(c ^ 1, 2, ktn);
              asm volatile("s_waitcnt vmcnt(4)" ::: "memory"); }
    else    { asm volatile("s_waitcnt vmcnt(2)" ::: "memory"); }
    __builtin_amdgcn_s_barrier();
    __builtin_amdgcn_sched_barrier(0);
#pragma unroll
    for (int i = 0; i < 4; ++i) {
      int row = wr * 128 + i * 16 + l16;   // A half 2*wr (ready)
      af[i][0] = RD_FRAG(As, c, row, 0);
      af[i][1] = RD_FRAG(As, c, row, 1);
    }
#pragma unroll
    for (int n = 0; n < 2; ++n) {
      int row = wc * 64 + n * 16 + l16;    // B half wc (ready)
      bfr[n][0] = RD_FRAG(Bs, c, row, 0);
      bfr[n][1] = RD_FRAG(Bs, c, row, 1);
    }
    asm volatile("s_waitcnt lgkmcnt(0)" ::: "memory");
    __builtin_amdgcn_sched_barrier(0);
    __builtin_amdgcn_s_setprio(1);
#pragma unroll
    for (int i = 0; i < 4; ++i)
#pragma unroll
      for (int n = 0; n < 2; ++n) {
        acc[i][n] = mfma16(af[i][0], bfr[n][0], acc[i][n]);
        acc[i][n] = mfma16(af[i][1], bfr[n][1], acc[i][n]);
      }
    __builtin_amdgcn_s_setprio(0);
    __builtin_amdgcn_s_barrier();
    // ---- phase 1 (mh=0, nh=1): issue {B0,B1} ----
#pragma unroll
    for (int n = 0; n < 2; ++n) {
      int row = wc * 64 + (2 + n) * 16 + l16;   // still B half wc (ready)
      bfr[2 + n][0] = RD_FRAG(Bs, c, row, 0);
      bfr[2 + n][1] = RD_FRAG(Bs, c, row, 1);
    }
    if (pf) { STG_B(c ^ 1, 0, ktn); STG_B(c ^ 1, 1, ktn); }
    __builtin_amdgcn_s_barrier();
    asm volatile("s_waitcnt lgkmcnt(0)" ::: "memory");
    __builtin_amdgcn_sched_barrier(0);
    __builtin_amdgcn_s_setprio(1);
#pragma unroll
    for (int i = 0; i < 4; ++i)
#pragma unroll
      for (int n = 0; n < 2; ++n) {
        acc[i][2 + n] = mfma16(af[i][0], bfr[2 + n][0], acc[i][2 + n]);
        acc[i][2 + n] = mfma16(af[i][1], bfr[2 + n][1], acc[i][2 + n]);
      }
    __builtin_amdgcn_s_setprio(0);
    __builtin_amdgcn_s_barrier();
    // ---- phase 2 (mh=1, nh=0): issue {B2,B3}, wait tile-j A1,A3; reads after barrier ----
    if (pf) { STG_B(c ^ 1, 2, ktn); STG_B(c ^ 1, 3, ktn);
              asm volatile("s_waitcnt vmcnt(6)" ::: "memory"); }
    else    { asm volatile("s_waitcnt vmcnt(0)" ::: "memory"); }
    __builtin_amdgcn_s_barrier();
    __builtin_amdgcn_sched_barrier(0);
#pragma unroll
    for (int i = 0; i < 4; ++i) {
      int row = wr * 128 + (4 + i) * 16 + l16;   // A half 2*wr+1 (just drained)
      af[i][0] = RD_FRAG(As, c, row, 0);
      af[i][1] = RD_FRAG(As, c, row, 1);
    }
    asm volatile("s_waitcnt lgkmcnt(0)" ::: "memory");
    __builtin_amdgcn_sched_barrier(0);
    __builtin_amdgcn_s_setprio(1);
#pragma unroll
    for (int i = 0; i < 4; ++i)
#pragma unroll
      for (int n = 0; n < 2; ++n) {
        acc[4 + i][n] = mfma16(af[i][0], bfr[n][0], acc[4 + i][n]);
        acc[4 + i][n] = mfma16(af[i][1], bfr[n][1], acc[4 + i][n]);
      }
    __builtin_amdgcn_s_setprio(0);
    __builtin_amdgcn_s_barrier();
    // ---- phase 3 (mh=1, nh=1): issue {A1,A3} ----
    if (pf) { STG_A(c ^ 1, 1, ktn); STG_A(c ^ 1, 3, ktn); }
    __builtin_amdgcn_s_barrier();
    __builtin_amdgcn_s_setprio(1);
#pragma unroll
    for (int i = 0; i < 4; ++i)
#pragma unroll
      for (int n = 0; n < 2; ++n) {
        acc[4 + i][2 + n] = mfma16(af[i][0], bfr[2 + n][0], acc[4 + i][2 + n]);
        acc[4 + i][2 + n] = mfma16(af[i][1], bfr[2 + n][1], acc[4 + i][2 + n]);
      }
    __builtin_amdgcn_s_setprio(0);
    __builtin_amdgcn_s_barrier();
    c ^= 1;
  }
#undef STG_A
#undef STG_B
#undef RD_FRAG
  if (EPI == 2) {
    // in-register SiLU-GU: acc[.][ni] = g, acc[.][ni+2] = u of same ff-col.
#pragma unroll
    for (int mi = 0; mi < 8; ++mi)
#pragma unroll
      for (int ni = 0; ni < 2; ++ni)
#pragma unroll
        for (int r = 0; r < 4; ++r) {
          float g = acc[mi][ni][r];
          float u = acc[mi][ni + 2][r];
          float s = g / (1.0f + __expf(-g));
          int row = bm + wr * 128 + mi * 16 + 4 * lg + r;
          int col = (bn >> 1) + wc * 32 + ni * 16 + l16;
          ((u16*)Cp)[(size_t)row * Nst + col] = f2bf(s * u);
        }
    return;
  }
#pragma unroll
  for (int mi = 0; mi < 8; ++mi)
#pragma unroll
    for (int ni = 0; ni < 4; ++ni)
#pragma unroll
      for (int r = 0; r < 4; ++r) {
        int row = bm + wr * 128 + mi * 16 + 4 * lg + r;
        int col = bn + wc * 64 + ni * 16 + l16;
        float val = acc[mi][ni][r];
        if (EPI == 0) {
          ((u16*)Cp)[(size_t)row * N + col] = f2bf(val);
        } else {
          if (col < Nst) ((float*)Cp)[(size_t)row * Nst + col] = val;
        }
      }
}

// ---------------- RoPE in-place, q+k heads in one launch (24 virtual heads) ----------------
__global__ void k_rope(u16* __restrict__ buf) {
  int idx = blockIdx.x * 256 + threadIdx.x;   // C_NTOK * 24 * 16 total
  int j = idx & 15;
  int h = (idx >> 4) % 24;
  int t = idx / (16 * 24);
  int pos = t & (C_S - 1);
  const float L = 13.122363377404328f;   // ln(500000)
  float inv0 = expf(-(float)(4 * j)     * (1.0f / C_HD) * L);
  float inv1 = expf(-(float)(4 * j + 2) * (1.0f / C_HD) * L);
  float a0 = (float)pos * inv0, a1 = (float)pos * inv1;
  float c0 = cosf(a0), s0 = sinf(a0), c1 = cosf(a1), s1 = sinf(a1);
  int hoff = (h < 16) ? h * C_HD : 1024 + (h - 16) * C_HD;
  u16* pp = buf + (size_t)t * 2048 + hoff + 2 * j;
  u32 lo = *(u32*)pp;
  u32 hi = *(u32*)(pp + 32);
  float x0a = bf2f((u16)lo), x0b = bf2f((u16)(lo >> 16));
  float x1a = bf2f((u16)hi), x1b = bf2f((u16)(hi >> 16));
  *(u32*)pp        = (u32)f2bf(x0a * c0 - x1a * s0) | ((u32)f2bf(x0b * c1 - x1b * s1) << 16);
  *(u32*)(pp + 32) = (u32)f2bf(x1a * c0 + x0a * s0) | ((u32)f2bf(x1b * c1 + x0b * s1) << 16);
}

// ---------------- fragment-order pack of K and V per 64-key tile (V via LDS transpose) ----
__global__ __launch_bounds__(256) void k_pack(const u16* __restrict__ qkv,
                                              u16* __restrict__ KP,
                                              u16* __restrict__ VP) {
  const int t = blockIdx.x, kvh = blockIdx.y, b = blockIdx.z;
  const int tid = threadIdx.x;
  __shared__ u16 T[64][72];
  {  // stage V tile [64 s][64 hd] coalesced
    const int r = tid >> 2, q = tid & 3;
    const u16* src = qkv + ((size_t)(b * C_S + 64 * t + r)) * 2048 + 1536 + kvh * C_HD + 16 * q;
    *(uint4*)&T[r][16 * q]     = *(const uint4*)src;
    *(uint4*)&T[r][16 * q + 8] = *(const uint4*)(src + 8);
  }
  __syncthreads();
  const int lane = tid & 63, i4 = tid >> 6;
  const int l16 = lane & 15, lg = lane >> 4;
  const size_t obase = (((size_t)((b * 8 + kvh) * 32 + t)) * 8) * 512 + (size_t)lane * 8;
#pragma unroll
  for (int r = 0; r < 2; ++r) {
    int inst = i4 + 4 * r;
    int jt = inst >> 1, h = inst & 1;
    const u16* ks = qkv + (size_t)(b * C_S + 64 * t + 16 * jt + l16) * 2048
                    + 1024 + kvh * C_HD + 32 * h + 8 * lg;
    *(uint4*)(KP + obase + (size_t)inst * 512) = *(const uint4*)ks;
    u16 vtmp[8];
#pragma unroll
    for (int j = 0; j < 8; ++j) vtmp[j] = T[32 * h + 8 * lg + j][16 * jt + l16];
    *(uint4*)(VP + obase + (size_t)inst * 512) = *(uint4*)vtmp;
  }
}

// ---------------- flash attention (paired) with fragment-packed K/V ----------
// Mask only the diagonal (last) tile; tree-reduced max/sum; exact skip-rescale.
__global__ __launch_bounds__(64) void k_attn(const u16* __restrict__ qkv,
                                             const u16* __restrict__ KP,
                                             const u16* __restrict__ VP,
                                             const float* __restrict__ bias,
                                             u16* __restrict__ o) {
  const int qp = blockIdx.x, h = blockIdx.y, b = blockIdx.z;
  const int kvh = h >> 1;
  const int lane = threadIdx.x;
  const int l16 = lane & 15, lg = lane >> 4;
  __shared__ u16 P[16][72];
  const float* biasb = bias + b * C_S;
  const u16* kpb = KP + ((size_t)((b * 8 + kvh) * 32) * 8) * 512 + (size_t)lane * 8;
  const u16* vpb = VP + ((size_t)((b * 8 + kvh) * 32) * 8) * 512 + (size_t)lane * 8;
#pragma unroll
  for (int half = 0; half < 2; ++half) {
    const int qt = half ? (127 - qp) : qp;
    const int q0 = qt * 16;
    const int qrow = q0 + l16;
    const u16* qbase = qkv + (size_t)(b * C_S + qrow) * 2048 + h * C_HD + 8 * lg;
    s16x8 qf0 = *(const s16x8*)qbase;
    s16x8 qf1 = *(const s16x8*)(qbase + 32);
    float m = -1e30f, lsum = 0.f;
    f32x4 accO[4];
#pragma unroll
    for (int f = 0; f < 4; ++f) accO[f] = (f32x4){0.f, 0.f, 0.f, 0.f};
    const int nt = (q0 + 16 + 63) >> 6;
    s16x8 kf[8], vf[8];
#pragma unroll
    for (int i = 0; i < 8; ++i) kf[i] = *(const s16x8*)(kpb + (size_t)i * 512);
#pragma unroll
    for (int i = 0; i < 8; ++i) vf[i] = *(const s16x8*)(vpb + (size_t)i * 512);
    for (int t = 0; t < nt; ++t) {
      const int kt = t * 64;
      f32x4 sc[4];
#pragma unroll
      for (int jt = 0; jt < 4; ++jt) sc[jt] = (f32x4){0.f, 0.f, 0.f, 0.f};
#pragma unroll
      for (int jt = 0; jt < 4; ++jt) {
        sc[jt] = mfma16(kf[2 * jt],     qf0, sc[jt]);
        sc[jt] = mfma16(kf[2 * jt + 1], qf1, sc[jt]);
      }
      if (t + 1 < nt) {
        const u16* kn = kpb + (size_t)(t + 1) * 8 * 512;
#pragma unroll
        for (int i = 0; i < 8; ++i) kf[i] = *(const s16x8*)(kn + (size_t)i * 512);
      }
      float mt4[4];
      if (t == nt - 1) {   // diagonal tile: causal mask needed
#pragma unroll
        for (int jt = 0; jt < 4; ++jt) {
          float4 bb = *(const float4*)&biasb[kt + 16 * jt + 4 * lg];
          int kv0 = kt + 16 * jt + 4 * lg;
          const float* bp = (const float*)&bb;
          float mj = -1e30f;
#pragma unroll
          for (int r = 0; r < 4; ++r) {
            float val = sc[jt][r] * 0.125f + bp[r];
            if (kv0 + r > qrow) val = -1e30f;
            sc[jt][r] = val;
            mj = fmaxf(mj, val);
          }
          mt4[jt] = mj;
        }
      } else {             // interior tile: no causal masking possible
#pragma unroll
        for (int jt = 0; jt < 4; ++jt) {
          float4 bb = *(const float4*)&biasb[kt + 16 * jt + 4 * lg];
          const float* bp = (const float*)&bb;
          float mj = -1e30f;
#pragma unroll
          for (int r = 0; r < 4; ++r) {
            float val = sc[jt][r] * 0.125f + bp[r];
            sc[jt][r] = val;
            mj = fmaxf(mj, val);
          }
          mt4[jt] = mj;
        }
      }
      float mt = fmaxf(fmaxf(mt4[0], mt4[1]), fmaxf(mt4[2], mt4[3]));
      mt = fmaxf(mt, __shfl_xor(mt, 16, 64));
      mt = fmaxf(mt, __shfl_xor(mt, 32, 64));
      if (__all(mt <= m)) {   // exact skip: cc would be 1
        float ps4[4];
#pragma unroll
        for (int jt = 0; jt < 4; ++jt) {
          float pj = 0.f;
#pragma unroll
          for (int r = 0; r < 4; ++r) {
            float pv = __expf(sc[jt][r] - m);
            sc[jt][r] = pv;
            pj += pv;
          }
          ps4[jt] = pj;
        }
        float ps = (ps4[0] + ps4[1]) + (ps4[2] + ps4[3]);
        ps += __shfl_xor(ps, 16, 64);
        ps += __shfl_xor(ps, 32, 64);
        lsum += ps;
      } else {
        float mn = fmaxf(m, mt);
        float cc = __expf(m - mn);
        m = mn;
        float ps4[4];
#pragma unroll
        for (int jt = 0; jt < 4; ++jt) {
          float pj = 0.f;
#pragma unroll
          for (int r = 0; r < 4; ++r) {
            float pv = __expf(sc[jt][r] - m);
            sc[jt][r] = pv;
            pj += pv;
          }
          ps4[jt] = pj;
        }
        float ps = (ps4[0] + ps4[1]) + (ps4[2] + ps4[3]);
        ps += __shfl_xor(ps, 16, 64);
        ps += __shfl_xor(ps, 32, 64);
        lsum = lsum * cc + ps;
#pragma unroll
        for (int f = 0; f < 4; ++f)
#pragma unroll
          for (int r = 0; r < 4; ++r) accO[f][r] *= cc;
      }
#pragma unroll
      for (int jt = 0; jt < 4; ++jt) {
        uint2 w;
        w.x = (u32)f2bf(sc[jt][0]) | ((u32)f2bf(sc[jt][1]) << 16);
        w.y = (u32)f2bf(sc[jt][2]) | ((u32)f2bf(sc[jt][3]) << 16);
        *(uint2*)&P[l16][16 * jt + 4 * lg] = w;
      }
      asm volatile("s_waitcnt lgkmcnt(0)" ::: "memory");   // DS writes retired
      __builtin_amdgcn_sched_barrier(0);                   // rule 18: pin MFMA below
      s16x8 pf0 = *(const s16x8*)&P[l16][8 * lg];
      s16x8 pf1 = *(const s16x8*)&P[l16][32 + 8 * lg];
#pragma unroll
      for (int f = 0; f < 4; ++f) {
        accO[f] = mfma16(vf[2 * f],     pf0, accO[f]);
        accO[f] = mfma16(vf[2 * f + 1], pf1, accO[f]);
      }
      if (t + 1 < nt) {
        const u16* vn = vpb + (size_t)(t + 1) * 8 * 512;
#pragma unroll
        for (int i = 0; i < 8; ++i) vf[i] = *(const s16x8*)(vn + (size_t)i * 512);
      }
    }
    float linv = 1.0f / lsum;
    u16* ob = o + ((size_t)(b * C_S + qrow)) * 1024 + h * C_HD + 4 * lg;
#pragma unroll
    for (int f = 0; f < 4; ++f) {
      uint2 w;
      w.x = (u32)f2bf(accO[f][0] * linv) | ((u32)f2bf(accO[f][1] * linv) << 16);
      w.y = (u32)f2bf(accO[f][2] * linv) | ((u32)f2bf(accO[f][3] * linv) << 16);
      *(uint2*)(ob + 16 * f) = w;
    }
  }
}

extern "C" void kernel_launch(void* const* d_in, const int* in_sizes, int n_in,
                              void* d_out, int out_size, void* d_ws, size_t ws_size,
                              hipStream_t stream) {
  const int*   ids  = (const int*)d_in[0];
  const float* emb  = (const float*)d_in[1];
  const float* Wq   = (const float*)d_in[2];
  const float* Wk   = (const float*)d_in[3];
  const float* Wv   = (const float*)d_in[4];
  const float* Wo   = (const float*)d_in[5];
  const float* Wg   = (const float*)d_in[6];
  const float* Wu   = (const float*)d_in[7];
  const float* Wd   = (const float*)d_in[8];
  const float* anw  = (const float*)d_in[9];
  const float* fnw  = (const float*)d_in[10];
  const float* finw = (const float*)d_in[11];
  const float* lmh  = (const float*)d_in[12];

  char* p = (char*)d_ws;
  float* x  = (float*)p; p += (size_t)C_NTOK * C_DIM * 4;
  u16* hn   = (u16*)p;   p += (size_t)C_NTOK * C_DIM * 2;
  u16* qkv  = (u16*)p;   p += (size_t)C_NTOK * 2048 * 2;
  u16* vtb  = (u16*)p;   p += (size_t)C_NTOK * C_NKVH * C_HD * 2;   // unused (kept for layout)
  u16* ao   = (u16*)p;   p += (size_t)C_NTOK * C_NH * C_HD * 2;
  u16* gu   = (u16*)p;   p += (size_t)C_NTOK * 2 * C_FF * 2;        // gu now [4096][4096] bf16
  u16* wT   = (u16*)p;   p += (size_t)8192 * 1024 * 2;
  float* bias = (float*)p; p += (size_t)C_NTOK * 4;
  u16* KP   = (u16*)p;   p += (size_t)C_B * 8 * 32 * 8 * 512 * 2;   // 4MB
  u16* VP   = (u16*)p;   p += (size_t)C_B * 8 * 32 * 8 * 512 * 2;   // 4MB
  u16* wTall = (u16*)p;
  (void)vtb;

  const size_t M1 = 1024 * 1024;               // 1M elems
  const size_t O_qkv = 0;                      // L x 2M (q@0, k@+1M, v@+1.5M)
  const size_t O_wo  = O_qkv + 16 * M1;        // L x 1M
  const size_t O_gu  = O_wo + 8 * M1;          // L x 8M (32-row interleaved g|u)
  const size_t O_wd  = O_gu + 64 * M1;         // L x 4M
  const size_t O_lmh = O_wd + 32 * M1;         // 4M
  const size_t wTall_elems = O_lmh + 4 * M1;   // 124M elems = 248MB
  const size_t needed = ((char*)wTall - (char*)d_ws) + wTall_elems * 2;
  const bool big = ws_size >= needed;

  k_embed<<<C_NTOK, 256, 0, stream>>>(ids, emb, x);
  k_bias<<<C_NTOK / 256, 256, 0, stream>>>(ids, bias);

  if (big) {
    k_wT<<<dim3(16, 16, 8), 256, 0, stream>>>(Wq, wTall + O_qkv, C_DIM, 1024, M1, 2 * M1, -1);
    k_wT<<<dim3(8, 16, 8), 256, 0, stream>>>(Wk, wTall + O_qkv + M1, C_DIM, 512, M1 / 2, 2 * M1, -1);
    k_wT<<<dim3(8, 16, 8), 256, 0, stream>>>(Wv, wTall + O_qkv + M1 + M1 / 2, C_DIM, 512, M1 / 2, 2 * M1, -1);
    k_wT<<<dim3(16, 16, 8), 256, 0, stream>>>(Wo, wTall + O_wo, 1024, C_DIM, M1, M1, -1);
    k_wT<<<dim3(64, 16, 8), 256, 0, stream>>>(Wg, wTall + O_gu, C_DIM, C_FF, 4 * M1, 8 * M1, 0);
    k_wT<<<dim3(64, 16, 8), 256, 0, stream>>>(Wu, wTall + O_gu, C_DIM, C_FF, 4 * M1, 8 * M1, 32);
    k_wT<<<dim3(16, 64, 8), 256, 0, stream>>>(Wd, wTall + O_wd, C_FF, C_DIM, 4 * M1, 4 * M1, -1);
    k_wT<<<dim3(64, 16, 1), 256, 0, stream>>>(lmh, wTall + O_lmh, C_DIM, C_V, 0, 0, -1);
  }

  for (int l = 0; l < C_NL; ++l) {
    k_rmsnorm<<<C_NTOK, 256, 0, stream>>>(x, anw + (size_t)l * C_DIM, hn);
    const u16* qkvT;
    if (big) {
      qkvT = wTall + O_qkv + (size_t)l * 2 * M1;
    } else {
      k_wT<<<dim3(16, 16), 256, 0, stream>>>(Wq + (size_t)l * M1, wT, C_DIM, 1024, 0, 0, -1);
      k_wT<<<dim3(8, 16), 256, 0, stream>>>(Wk + (size_t)l * M1 / 2, wT + M1, C_DIM, 512, 0, 0, -1);
      k_wT<<<dim3(8, 16), 256, 0, stream>>>(Wv + (size_t)l * M1 / 2, wT + M1 + M1 / 2, C_DIM, 512, 0, 0, -1);
      qkvT = wT;
    }
    k_gemm<0, 1><<<dim3(16, 32), 256, 0, stream>>>(hn, qkvT, qkv, 2048, C_DIM, C_DIM);
    k_rope<<<C_NTOK * 24 * 16 / 256, 256, 0, stream>>>(qkv);
    k_pack<<<dim3(32, C_NKVH, C_B), 256, 0, stream>>>(qkv, KP, VP);
    k_attn<<<dim3(64, C_NH, C_B), 64, 0, stream>>>(qkv, KP, VP, bias, ao);
    const u16* woT;
    if (big) {
      woT = wTall + O_wo + (size_t)l * M1;
    } else {
      k_wT<<<dim3(16, 16), 256, 0, stream>>>(Wo + (size_t)l * M1, wT, 1024, C_DIM, 0, 0, -1);
      woT = wT;
    }
    k_gemm<2, 2><<<dim3(8, 32, 2), 256, 0, stream>>>(ao, woT, x, C_DIM, 1024, 1024);
    k_rmsnorm<<<C_NTOK, 256, 0, stream>>>(x, fnw + (size_t)l * C_DIM, hn);
    const u16* guT;
    if (big) {
      guT = wTall + O_gu + (size_t)l * 8 * M1;
    } else {
      k_wT<<<dim3(64, 16), 256, 0, stream>>>(Wg + (size_t)l * 4 * M1, wT, C_DIM, C_FF, 0, 0, 0);
      k_wT<<<dim3(64, 16), 256, 0, stream>>>(Wu + (size_t)l * 4 * M1, wT, C_DIM, C_FF, 0, 0, 32);
      guT = wT;
    }
    k_gemm256<2><<<dim3(32, 16), 512, 0, stream>>>(hn, guT, gu, 8192, C_DIM, C_DIM, 4096);
    const u16* wdT;
    if (big) {
      wdT = wTall + O_wd + (size_t)l * 4 * M1;
    } else {
      k_wT<<<dim3(16, 64), 256, 0, stream>>>(Wd + (size_t)l * 4 * M1, wT, C_FF, C_DIM, 0, 0, -1);
      wdT = wT;
    }
    k_gemm<2, 4><<<dim3(8, 32, 4), 256, 0, stream>>>(gu, wdT, x, C_DIM, C_FF, 4096);
  }
  k_rmsnorm<<<C_NTOK, 256, 0, stream>>>(x, finw, hn);
  const u16* lmhT;
  if (big) {
    lmhT = wTall + O_lmh;
  } else {
    k_wT<<<dim3(64, 16), 256, 0, stream>>>(lmh, wT, C_DIM, C_V, 0, 0, -1);
    lmhT = wT;
  }
  k_gemm256<1><<<dim3(16, 16), 512, 0, stream>>>(hn, lmhT, d_out, 4096, C_DIM, C_DIM, C_V);
}